// Round 18
// baseline (312.434 us; speedup 1.0000x reference)
//
#include <hip/hip_runtime.h>
#include <stdint.h>

#define S_LEN 2048
#define BATCH 4
#define HID   2048
#define HD    128
#define NKV   4
#define MTOT  (BATCH*S_LEN) // 8192
#define NQT2  (S_LEN/256)   // 8 q-tiles (256 rows) per (b,h)
#define QSCALE 0.08838834764831845f
#define LOG2E  1.4426950408889634f

// native v_exp_f32 (2^x)
#define EXP2F(x) __builtin_amdgcn_exp2f(x)

typedef float    f32x4  __attribute__((ext_vector_type(4)));
typedef __bf16   bf16x8 __attribute__((ext_vector_type(8)));
typedef __bf16   bf16x4 __attribute__((ext_vector_type(4)));
typedef unsigned u32x2  __attribute__((ext_vector_type(2)));

// async global->LDS, 16B per lane. LDS dest = wave-uniform base + lane*16.
__device__ __forceinline__ void gld16(const void* g, void* l) {
    __builtin_amdgcn_global_load_lds(
        (const __attribute__((address_space(1))) void*)g,
        (__attribute__((address_space(3))) void*)l, 16, 0, 0);
}

// ---------------- fp32 -> bf16 bulk convert (8 elems/thread) ----------------
__global__ void k_conv_x(const float* __restrict__ in, __bf16* __restrict__ out) {
    int i = blockIdx.x * blockDim.x + threadIdx.x;
    f32x4 a = ((const f32x4*)in)[2 * i];
    f32x4 b = ((const f32x4*)in)[2 * i + 1];
    bf16x8 o;
    o[0] = (__bf16)a[0]; o[1] = (__bf16)a[1]; o[2] = (__bf16)a[2]; o[3] = (__bf16)a[3];
    o[4] = (__bf16)b[0]; o[5] = (__bf16)b[1]; o[6] = (__bf16)b[2]; o[7] = (__bf16)b[3];
    ((bf16x8*)out)[i] = o;
}

// ---- ALL weight transposes in one launch: W [K][N] fp32 -> Wt [N][K] bf16 --
__global__ void k_transpose_all(const float* __restrict__ Wq,
                                const float* __restrict__ Wk,
                                const float* __restrict__ Wv,
                                const float* __restrict__ Wo,
                                __bf16* __restrict__ wqt,
                                __bf16* __restrict__ wkvt,
                                __bf16* __restrict__ wot) {
    const int z = blockIdx.z;
    const float* in; __bf16* out; int N;
    if      (z == 0) { in = Wq; out = wqt;  N = 2048; }
    else if (z == 1) { in = Wk; out = wkvt; N = 512;  }
    else if (z == 2) { in = Wv; out = wkvt + (size_t)512 * HID; N = 512; }
    else             { in = Wo; out = wot;  N = 2048; }
    int k0 = blockIdx.x * 64, n0 = blockIdx.y * 64;
    if (n0 >= N) return;
    __shared__ float tile[64][65];
    for (int e = threadIdx.x; e < 4096; e += 256) {
        int r = e >> 6, c = e & 63;
        tile[r][c] = in[(size_t)(k0 + r) * N + n0 + c];
    }
    __syncthreads();
    for (int e = threadIdx.x; e < 4096; e += 256) {
        int r = e >> 6, c = e & 63;
        out[(size_t)(n0 + r) * HID + k0 + c] = (__bf16)tile[c][r];
    }
}

// ============== 8-phase deep-pipeline K-loop (validated R13) ================
// Barriers MUST be memory-fenced asm ("s_barrier" ::: "memory"): the bare
// builtin is IntrNoMem and the compiler hoists ds_reads across it (R12 race).
#define BARM asm volatile("s_barrier" ::: "memory")
#define BAR1 do { BARM;                                                       \
                  asm volatile("s_waitcnt lgkmcnt(0)" ::: "memory");          \
                  __builtin_amdgcn_sched_barrier(0); } while (0)
#define BAR2 BARM
#define MM(qm, qn)                                                            \
    do {                                                                      \
        __builtin_amdgcn_s_setprio(1);                                        \
        _Pragma("unroll") for (int ks = 0; ks < 2; ks++)                      \
        _Pragma("unroll") for (int mf = 0; mf < 4; mf++)                      \
        _Pragma("unroll") for (int nf = 0; nf < 2; nf++)                      \
            acc[qm][qn][mf][nf] = __builtin_amdgcn_mfma_f32_16x16x32_bf16(    \
                af[mf][ks], bf[nf][ks], acc[qm][qn][mf][nf], 0, 0, 0);        \
        __builtin_amdgcn_s_setprio(0);                                        \
    } while (0)

// The shared 8-phase K-loop body (BM=BN=256, BK=64, 8 waves 2Mx4N, K=2048,
// LDS 128 KiB). Declares Ab/Bb/acc/af/bf and runs the full 16-iteration loop.
#define GEMM8_BODY(Aptr, Bptr)                                                \
    __shared__ __bf16 Ab[2][2][128 * 64];                                     \
    __shared__ __bf16 Bb[2][2][128 * 64];                                     \
    const int tid = threadIdx.x, lane = tid & 63, wave = tid >> 6;            \
    const int wm = wave >> 2, wn = wave & 3;                                  \
    const int lo = lane & 15, hi = lane >> 4;                                 \
    f32x4 acc[2][2][4][2] = {};                                               \
    const int srow = wave * 8 + (lane >> 3);                                  \
    const int sp   = lane & 7;                                                \
    auto STA = [&](int s, int h, int t) {                                     \
        _Pragma("unroll") for (int p = 0; p < 2; p++) {                       \
            int rr = p * 64 + srow;                                           \
            int c = sp ^ (rr & 7);                                            \
            gld16(Aptr + (size_t)(m0 + h * 128 + rr) * HID + t * 64 + c * 8,  \
                  &Ab[s][h][(p * 64 + wave * 8) * 64]);                       \
        }                                                                     \
    };                                                                        \
    auto STB = [&](int s, int h, int t) {                                     \
        _Pragma("unroll") for (int p = 0; p < 2; p++) {                       \
            int rr = p * 64 + srow;                                           \
            int c = sp ^ (rr & 7);                                            \
            gld16(Bptr + (size_t)(n0 + h * 128 + rr) * HID + t * 64 + c * 8,  \
                  &Bb[s][h][(p * 64 + wave * 8) * 64]);                       \
        }                                                                     \
    };                                                                        \
    bf16x8 af[4][2], bf[2][2];                                                \
    auto LDA = [&](int s, int qm) {                                           \
        _Pragma("unroll") for (int mf = 0; mf < 4; mf++) {                    \
            int rr = wm * 64 + mf * 16 + lo;                                  \
            _Pragma("unroll") for (int ks = 0; ks < 2; ks++) {                \
                int pp = (ks * 4 + hi) ^ (rr & 7);                            \
                af[mf][ks] = *(const bf16x8*)&Ab[s][qm][rr * 64 + pp * 8];    \
            }                                                                 \
        }                                                                     \
    };                                                                        \
    auto LDB = [&](int s, int qn) {                                           \
        _Pragma("unroll") for (int nf = 0; nf < 2; nf++) {                    \
            int rr = wn * 32 + nf * 16 + lo;                                  \
            _Pragma("unroll") for (int ks = 0; ks < 2; ks++) {                \
                int pp = (ks * 4 + hi) ^ (rr & 7);                            \
                bf[nf][ks] = *(const bf16x8*)&Bb[s][qn][rr * 64 + pp * 8];    \
            }                                                                 \
        }                                                                     \
    };                                                                        \
    STA(0, 0, 0); STB(0, 0, 0); STA(0, 1, 0); STB(0, 1, 0);                   \
    STA(1, 1, 1); STB(1, 1, 1);                                               \
    asm volatile("s_waitcnt vmcnt(4)" ::: "memory");                          \
    BARM;                                                                     \
    _Pragma("unroll 1")                                                       \
    for (int i = 0; i < 16; i++) {                                            \
        const int t0 = 2 * i, t1 = 2 * i + 1;                                 \
        const bool more = (i < 15);                                           \
        LDA(0, 0); LDB(0, 0);                                                 \
        STA(1, 0, t1); STB(1, 0, t1);                                         \
        BAR1; MM(0, 0); BAR2;                                                 \
        LDB(0, 1);                                                            \
        BAR1; MM(0, 1); BAR2;                                                 \
        LDA(0, 1); LDB(0, 0);                                                 \
        if (more) STA(0, 0, t0 + 2);                                          \
        BAR1; MM(1, 0); BAR2;                                                 \
        LDB(0, 1);                                                            \
        if (more) STB(0, 0, t0 + 2);                                          \
        BAR1; MM(1, 1);                                                       \
        if (more) { asm volatile("s_waitcnt vmcnt(4)" ::: "memory"); }        \
        else      { asm volatile("s_waitcnt vmcnt(0)" ::: "memory"); }        \
        BAR2;                                                                 \
        LDA(1, 1); LDB(1, 1);                                                 \
        if (more) { STA(0, 1, t0 + 2); STB(0, 1, t0 + 2); }                   \
        BAR1; MM(1, 1); BAR2;                                                 \
        LDB(1, 0);                                                            \
        BAR1; MM(1, 0); BAR2;                                                 \
        LDA(1, 0); LDB(1, 1);                                                 \
        if (more) STA(1, 1, t1 + 2);                                          \
        BAR1; MM(0, 1); BAR2;                                                 \
        LDB(1, 0);                                                            \
        if (more) STB(1, 1, t1 + 2);                                          \
        BAR1; MM(0, 0);                                                       \
        if (more) { asm volatile("s_waitcnt vmcnt(4)" ::: "memory"); }        \
        BAR2;                                                                 \
    }

// -------- Q-proj GEMM, 8-phase: qb8 fp8 = rope(xb*wqt^T)*QSCALE*log2e -------
// grid 256 = (m 32) x (n 8) = exactly 1 block/CU. log2e folded into the fp8
// scale so k_attn's softmax can use native exp2 (v_exp_f32).
__global__ __launch_bounds__(512) void k_gemm_q8(const __bf16* __restrict__ A,
                                                 const __bf16* __restrict__ Bt,
                                                 unsigned char* __restrict__ qb8,
                                                 const float* __restrict__ cosp,
                                                 const float* __restrict__ sinp) {
    const int m0 = (blockIdx.x >> 3) * 256;
    const int n0 = (blockIdx.x & 7) * 256;
    GEMM8_BODY(A, Bt)

    // epilogue: per-quadrant LDS stage -> rope + scale + fp8 -> store.
    __bf16* Cs = (__bf16*)&Ab[0][0][0];            // [128][132]
    const int crow = tid >> 4;                     // 0..31 (+32 per rep)
    const int cch  = tid & 15;                     // 8-col chunk
    const int d0 = cch * 8;
    const float QS2 = QSCALE * LOG2E;
#pragma unroll
    for (int qm = 0; qm < 2; qm++)
#pragma unroll
        for (int qn = 0; qn < 2; qn++) {
#pragma unroll
            for (int mf = 0; mf < 4; mf++)
#pragma unroll
                for (int nf = 0; nf < 2; nf++) {
                    int rl = wm * 64 + mf * 16 + hi * 4;
                    int cl = wn * 32 + nf * 16 + lo;
#pragma unroll
                    for (int r = 0; r < 4; r++)
                        Cs[(rl + r) * 132 + cl] = (__bf16)acc[qm][qn][mf][nf][r];
                }
            __syncthreads();
#pragma unroll
            for (int rep = 0; rep < 4; rep++) {
                int row = rep * 32 + crow;
                int rowg = m0 + qm * 128 + row;
                int colg = n0 + qn * 128 + cch * 8;
                bf16x8 v = *(const bf16x8*)&Cs[row * 132 + cch * 8];
                float f[8];
#pragma unroll
                for (int j = 0; j < 8; j++) f[j] = (float)v[j];
                int s = rowg & (S_LEN - 1);
                f32x4 c0 = *(const f32x4*)&cosp[s * HD + d0];
                f32x4 c1 = *(const f32x4*)&cosp[s * HD + d0 + 4];
                f32x4 s0 = *(const f32x4*)&sinp[s * HD + d0];
                f32x4 s1 = *(const f32x4*)&sinp[s * HD + d0 + 4];
                float cc[8] = {c0[0], c0[1], c0[2], c0[3], c1[0], c1[1], c1[2], c1[3]};
                float ss[8] = {s0[0], s0[1], s0[2], s0[3], s1[0], s1[1], s1[2], s1[3]};
#pragma unroll
                for (int p = 0; p < 4; p++) {
                    float e0 = f[2 * p], e1 = f[2 * p + 1];
                    f[2 * p]     = (e0 * cc[2 * p]     - e1 * ss[2 * p])     * QS2;
                    f[2 * p + 1] = (e1 * cc[2 * p + 1] + e0 * ss[2 * p + 1]) * QS2;
                }
                int u0 = __builtin_amdgcn_cvt_pk_fp8_f32(f[0], f[1], 0, false);
                u0     = __builtin_amdgcn_cvt_pk_fp8_f32(f[2], f[3], u0, true);
                int u1 = __builtin_amdgcn_cvt_pk_fp8_f32(f[4], f[5], 0, false);
                u1     = __builtin_amdgcn_cvt_pk_fp8_f32(f[6], f[7], u1, true);
                u32x2 pk; pk[0] = (unsigned)u0; pk[1] = (unsigned)u1;
                *(u32x2*)&qb8[(size_t)rowg * HID + colg] = pk;
            }
            __syncthreads();
        }
}

// -------- O-proj GEMM, 8-phase (validated R13): out[8192][2048] f32 ---------
__global__ __launch_bounds__(512) void k_gemm_o8(const __bf16* __restrict__ A,
                                                 const __bf16* __restrict__ Bt,
                                                 float* __restrict__ Cp) {
    const int m0 = (blockIdx.x >> 3) * 256;
    const int n0 = (blockIdx.x & 7) * 256;
    GEMM8_BODY(A, Bt)

#pragma unroll
    for (int qm = 0; qm < 2; qm++)
#pragma unroll
        for (int qn = 0; qn < 2; qn++)
#pragma unroll
            for (int mf = 0; mf < 4; mf++)
#pragma unroll
                for (int nf = 0; nf < 2; nf++) {
                    int row = m0 + qm * 128 + wm * 64 + mf * 16 + hi * 4;
                    int col = n0 + qn * 128 + wn * 32 + nf * 16 + lo;
#pragma unroll
                    for (int r = 0; r < 4; r++)
                        Cp[(size_t)(row + r) * HID + col] = acc[qm][qn][mf][nf][r];
                }
}

// ---- KV-proj GEMM, 4-phase deep pipeline: C[8192][1024] = xb * wkvt^T ------
// BM=256, BN=128, BK=64, 8 waves (2M x 4N, wave tile 64x32 per qm half).
// LDS: A 2slot x 2half x 8K = 64K, B 2slot x 16K = 32K -> 96 KB, 1 block/CU.
// grid 256 = (m 32) x (n 8) = exactly 1/CU. 4 phases per iteration (2 K-tiles).
// Stage plan (hazard ledger): P1 -> t1{A-h1,B} (slot1 h1/B last read prev
// P4/P3, barriers passed); P2 -> next-t0{A-h0,B} (slot0 h0/B last read P1);
// P3 -> next-t0{A-h1} (h1 last read P2); P4 -> next-t1{A-h0} (h0 last read P3).
// Counted vmcnt: P2=4 (drain t1; next-t0's 4 newest stay in flight),
// P4=2 (drain next-t0; next-t1-Ah0's 2 stay in flight). Final iter drains 0.
// Epilogue: cols 2048-2559 -> K rope+fp8 -> kb8; 2560-3071 -> V^T -> vtb.
__global__ __launch_bounds__(512) void k_gemm_kv8(const __bf16* __restrict__ A,
                                                  const __bf16* __restrict__ Bt,
                                                  unsigned char* __restrict__ kb8,
                                                  __bf16* __restrict__ vtb,
                                                  const float* __restrict__ cosp,
                                                  const float* __restrict__ sinp) {
    __shared__ __bf16 Ab[2][2][128 * 64];   // [slot][half] 64 KB
    __shared__ __bf16 Bb[2][128 * 64];      // [slot]       32 KB
    const int tid = threadIdx.x, lane = tid & 63, wave = tid >> 6;
    const int wm = wave >> 2, wn = wave & 3;
    const int m0 = (blockIdx.x >> 3) * 256;
    const int n0 = 2048 + (blockIdx.x & 7) * 128;
    const int lo = lane & 15, hi = lane >> 4;
    f32x4 acc[2][4][2] = {};                // [qm][mf][nf]

    const int srow = wave * 8 + (lane >> 3);
    const int sp   = lane & 7;

    auto STA = [&](int s, int h, int t) {   // 2 gld16
#pragma unroll
        for (int p = 0; p < 2; p++) {
            int rr = p * 64 + srow;
            int c = sp ^ (rr & 7);
            gld16(A + (size_t)(m0 + h * 128 + rr) * HID + t * 64 + c * 8,
                  &Ab[s][h][(p * 64 + wave * 8) * 64]);
        }
    };
    auto STB = [&](int s, int t) {          // 2 gld16
#pragma unroll
        for (int p = 0; p < 2; p++) {
            int rr = p * 64 + srow;
            int c = sp ^ (rr & 7);
            gld16(Bt + (size_t)(n0 + rr) * HID + t * 64 + c * 8,
                  &Bb[s][(p * 64 + wave * 8) * 64]);
        }
    };

    bf16x8 af[4][2], bf[2][2];
    auto LDA = [&](int s, int qm) {         // 8 ds_read_b128
#pragma unroll
        for (int mf = 0; mf < 4; mf++) {
            int rr = wm * 64 + mf * 16 + lo;
#pragma unroll
            for (int ks = 0; ks < 2; ks++) {
                int pp = (ks * 4 + hi) ^ (rr & 7);
                af[mf][ks] = *(const bf16x8*)&Ab[s][qm][rr * 64 + pp * 8];
            }
        }
    };
    auto LDB = [&](int s) {                 // 4 ds_read_b128
#pragma unroll
        for (int nf = 0; nf < 2; nf++) {
            int rr = wn * 32 + nf * 16 + lo;
#pragma unroll
            for (int ks = 0; ks < 2; ks++) {
                int pp = (ks * 4 + hi) ^ (rr & 7);
                bf[nf][ks] = *(const bf16x8*)&Bb[s][rr * 64 + pp * 8];
            }
        }
    };

#define MMKV(qm)                                                              \
    do {                                                                      \
        __builtin_amdgcn_s_setprio(1);                                        \
        _Pragma("unroll") for (int ks = 0; ks < 2; ks++)                      \
        _Pragma("unroll") for (int mf = 0; mf < 4; mf++)                      \
        _Pragma("unroll") for (int nf = 0; nf < 2; nf++)                      \
            acc[qm][mf][nf] = __builtin_amdgcn_mfma_f32_16x16x32_bf16(        \
                af[mf][ks], bf[nf][ks], acc[qm][mf][nf], 0, 0, 0);            \
        __builtin_amdgcn_s_setprio(0);                                        \
    } while (0)

    // prologue: t0 fully (slot0: A-h0,A-h1,B = 6), t1 A-h0 only (slot1: 2).
    STA(0, 0, 0); STA(0, 1, 0); STB(0, 0);
    STA(1, 0, 1);
    asm volatile("s_waitcnt vmcnt(2)" ::: "memory");  // t0 landed; t1-Ah0 flies
    BARM;

#pragma unroll 1
    for (int i = 0; i < 16; i++) {
        const int t0 = 2 * i, t1 = 2 * i + 1;
        const bool more = (i < 15);
        // P1: t0 qm=0   [stages t1 A-h1 + t1 B -> slot1]
        LDA(0, 0); LDB(0);
        STA(1, 1, t1); STB(1, t1);
        BAR1; MMKV(0); BAR2;
        // P2: t0 qm=1   [B frags retained; stages next-t0 A-h0 + B]
        LDA(0, 1);
        if (more) { STA(0, 0, t0 + 2); STB(0, t0 + 2); }
        BAR1; MMKV(1);
        if (more) { asm volatile("s_waitcnt vmcnt(4)" ::: "memory"); }
        else      { asm volatile("s_waitcnt vmcnt(0)" ::: "memory"); }
        BAR2;
        // P3: t1 qm=0   [stages next-t0 A-h1 (slot0 h1 free after P2)]
        LDA(1, 0); LDB(1);
        if (more) STA(0, 1, t0 + 2);
        BAR1; MMKV(0); BAR2;
        // P4: t1 qm=1   [stages next-t1 A-h0 (slot1 h0 free after P3)]
        LDA(1, 1);
        if (more) STA(1, 0, t1 + 2);
        BAR1; MMKV(1);
        if (more) { asm volatile("s_waitcnt vmcnt(2)" ::: "memory"); }
        BAR2;
    }

    // ---------------- epilogue (per 128-row qm half) -------------------------
    if (n0 < 2560) {
        // K: rope (no log2e; Q carries it) + fp8 pack -> kb8[8192][512]
        __bf16* Cs = (__bf16*)&Ab[0][0][0];         // [128][132]
        const int crow = tid >> 4;                  // 0..31 (+32 per rep)
        const int cch  = tid & 15;                  // 8-col chunk (128 cols)
        const int d0 = cch * 8;                     // n0 % 128 == 0
#pragma unroll
        for (int qm = 0; qm < 2; qm++) {
#pragma unroll
            for (int mf = 0; mf < 4; mf++)
#pragma unroll
                for (int nf = 0; nf < 2; nf++) {
                    int rl = wm * 64 + mf * 16 + hi * 4;
                    int cl = wn * 32 + nf * 16 + lo;
#pragma unroll
                    for (int r = 0; r < 4; r++)
                        Cs[(rl + r) * 132 + cl] = (__bf16)acc[qm][mf][nf][r];
                }
            __syncthreads();
#pragma unroll
            for (int rep = 0; rep < 4; rep++) {
                int row = rep * 32 + crow;
                int rowg = m0 + qm * 128 + row;
                int colg = n0 + cch * 8;
                bf16x8 v = *(const bf16x8*)&Cs[row * 132 + cch * 8];
                float f[8];
#pragma unroll
                for (int j = 0; j < 8; j++) f[j] = (float)v[j];
                int s = rowg & (S_LEN - 1);
                f32x4 c0 = *(const f32x4*)&cosp[s * HD + d0];
                f32x4 c1 = *(const f32x4*)&cosp[s * HD + d0 + 4];
                f32x4 s0 = *(const f32x4*)&sinp[s * HD + d0];
                f32x4 s1 = *(const f32x4*)&sinp[s * HD + d0 + 4];
                float cc[8] = {c0[0], c0[1], c0[2], c0[3], c1[0], c1[1], c1[2], c1[3]};
                float ss[8] = {s0[0], s0[1], s0[2], s0[3], s1[0], s1[1], s1[2], s1[3]};
#pragma unroll
                for (int p = 0; p < 4; p++) {
                    float e0 = f[2 * p], e1 = f[2 * p + 1];
                    f[2 * p]     = e0 * cc[2 * p]     - e1 * ss[2 * p];
                    f[2 * p + 1] = e1 * cc[2 * p + 1] + e0 * ss[2 * p + 1];
                }
                int u0 = __builtin_amdgcn_cvt_pk_fp8_f32(f[0], f[1], 0, false);
                u0     = __builtin_amdgcn_cvt_pk_fp8_f32(f[2], f[3], u0, true);
                int u1 = __builtin_amdgcn_cvt_pk_fp8_f32(f[4], f[5], 0, false);
                u1     = __builtin_amdgcn_cvt_pk_fp8_f32(f[6], f[7], u1, true);
                u32x2 pk; pk[0] = (unsigned)u0; pk[1] = (unsigned)u1;
                *(u32x2*)&kb8[(size_t)rowg * 512 + (colg - 2048)] = pk;
            }
            __syncthreads();
        }
    } else {
        // V: transposed stage CsT[col][row] -> vtb[plane][d][s]
        __bf16* CsT = (__bf16*)&Ab[0][0][0];        // [128 cols][132 rows pad]
        const int kvh = (n0 - 2560) >> 7;           // one kv head per block
        const int bb = m0 >> 11;                    // 256-row tile: one batch
        const int s0 = m0 & (S_LEN - 1);
        __bf16* dst = vtb + (size_t)(bb * NKV + kvh) * HD * S_LEN;
        const int dloc = tid >> 4;                  // 0..31 (+32 per rep)
        const int sch  = tid & 15;                  // 8-elem s chunk
#pragma unroll
        for (int qm = 0; qm < 2; qm++) {
#pragma unroll
            for (int mf = 0; mf < 4; mf++)
#pragma unroll
                for (int nf = 0; nf < 2; nf++) {
                    int cl = wn * 32 + nf * 16 + lo;
                    int mrow = wm * 64 + mf * 16 + hi * 4;
                    bf16x4 w;
#pragma unroll
                    for (int r = 0; r < 4; r++) w[r] = (__bf16)acc[qm][mf][nf][r];
                    *(bf16x4*)&CsT[cl * 132 + mrow] = w;
                }
            __syncthreads();
#pragma unroll
            for (int rep = 0; rep < 4; rep++) {
                int d = rep * 32 + dloc;
                bf16x8 v = *(const bf16x8*)&CsT[d * 132 + sch * 8];
                *(bf16x8*)&dst[(size_t)d * S_LEN + s0 + qm * 128 + sch * 8] = v;
            }
            __syncthreads();
        }
    }
#undef MMKV
}

// ----------------------------- flash attention ------------------------------
// KVBLK=128; QK^T fp8 (Q pre-scaled by QSCALE*log2e -> native exp2 softmax).
// PV bf16 in two 64-kv halves via wave-private Ps. LDS-throughput-bound
// (~816 cyc/wave/tile model matches 100us measured).
// LDS: Ks8 2x16K + Vs 2x32K + Ps 32K = 128 KB. Grid 256 = 1/CU.
__global__ __launch_bounds__(512) void k_attn(const unsigned char* __restrict__ qb8,
                                              const unsigned char* __restrict__ kb8,
                                              const __bf16* __restrict__ vtb,
                                              __bf16* __restrict__ ob) {
    __shared__ char   Ks8[2][128 * 128];  // [kv][128B fp8 d], 8-chunk XOR swz
    __shared__ __bf16 Vs[2][128 * 128];   // [d][kv 128] bf16, 16-chunk XOR swz
    __shared__ __bf16 Ps[8][2048];        // wave-private: 2 subtiles x 16x64
    const int tid = threadIdx.x, lane = tid & 63, wave = tid >> 6;
    const int pair = blockIdx.x, h = blockIdx.y, b = blockIdx.z;
    const int kvh = h >> 2;
    const int lo = lane & 15, hi = lane >> 4;
    char* PsW = (char*)&Ps[wave][0];

    const unsigned char* kbb = kb8 + (size_t)b * S_LEN * 512 + kvh * HD;
    const __bf16* vbb = vtb + (size_t)(b * NKV + kvh) * HD * S_LEN;

    const int krow_s = tid >> 3;                // 0..63 (+64 per round)
    const int kp_s   = tid & 7;
    const int vrow_s = tid >> 4;                // 0..31 (+32 per round)
    const int vp_s   = tid & 15;

    auto STAGE_K = [&](int buf, int t) {        // 16 KB: 2 gld16 rounds
#pragma unroll
        for (int r = 0; r < 2; r++) {
            int row = r * 64 + krow_s;
            int c = kp_s ^ (row & 7);
            gld16(kbb + (size_t)(t * 128 + row) * 512 + c * 16,
                  &Ks8[buf][(r * 64 + wave * 8) * 128]);
        }
    };
    auto STAGE_V = [&](int buf, int t) {        // 32 KB: 4 gld16 rounds
#pragma unroll
        for (int r = 0; r < 4; r++) {
            int row = r * 32 + vrow_s;          // d-row
            int c = vp_s ^ (row & 15);
            gld16(vbb + (size_t)row * S_LEN + t * 128 + c * 8,
                  &Vs[buf][(r * 32 + wave * 4) * 128]);
        }
    };

    // online softmax over 32 in-lane scores (exp2 domain; T13 defer thr=8)
    auto SM = [&](f32x4 (&sc)[8], float& Mr, float& Lr, f32x4 (&o)[8]) {
        float mloc = sc[0][0];
#pragma unroll
        for (int nt = 0; nt < 8; nt++)
#pragma unroll
            for (int r = 0; r < 4; r++) mloc = fmaxf(mloc, sc[nt][r]);
        mloc = fmaxf(mloc, __shfl_xor(mloc, 16, 64));
        mloc = fmaxf(mloc, __shfl_xor(mloc, 32, 64));
        float mn = (mloc <= Mr + 8.f) ? Mr : mloc;
        float sum = 0.f;
#pragma unroll
        for (int nt = 0; nt < 8; nt++)
#pragma unroll
            for (int r = 0; r < 4; r++) {
                float e = EXP2F(sc[nt][r] - mn);
                sc[nt][r] = e;
                sum += e;
            }
        sum += __shfl_xor(sum, 16, 64);
        sum += __shfl_xor(sum, 32, 64);
        if (mn != Mr) {
            float scl = EXP2F(Mr - mn);
            Lr = Lr * scl + sum;
            Mr = mn;
#pragma unroll
            for (int dt = 0; dt < 8; dt++) o[dt] *= scl;
        } else {
            Lr += sum;
        }
    };

#pragma unroll 1
    for (int pi = 0; pi < 2; pi++) {
        const int qt = pi ? (NQT2 - 1 - pair) : pair;  // 256-row q-tile index
        const int nkv = 2 * qt + 2;                    // kv tiles of 128 rows
        const int qbase = qt * 256 + wave * 32;        // this wave's 32 q-rows

        const unsigned char* qp0 = qb8 + (size_t)(b * S_LEN + qbase + lo) * HID + h * HD;
        const unsigned char* qp1 = qp0 + (size_t)16 * HID;
        long qa0[4], qa1[4];
#pragma unroll
        for (int kf = 0; kf < 4; kf++) {
            qa0[kf] = *(const long*)(qp0 + kf * 32 + hi * 8);
            qa1[kf] = *(const long*)(qp1 + kf * 32 + hi * 8);
        }

        f32x4 o0[8] = {}, o1[8] = {};
        float Mr0 = -3e30f, Lr0 = 0.f, Mr1 = -3e30f, Lr1 = 0.f;

        int cur = 0;
        if (pi == 1) __syncthreads();
        STAGE_K(0, 0);
        STAGE_V(0, 0);
        __syncthreads();

#pragma unroll 1
        for (int t = 0; t < nkv; t++) {
            if (t < nkv - 1) { STAGE_K(cur ^ 1, t + 1); STAGE_V(cur ^ 1, t + 1); }

            // S^T = K Q^T (fp8), 8 nt-rows of 16 kv, both subtiles share K
            f32x4 sc0[8], sc1[8];
            __builtin_amdgcn_s_setprio(1);
#pragma unroll
            for (int nt = 0; nt < 8; nt++) {
                f32x4 a = {0.f, 0.f, 0.f, 0.f}, bb = {0.f, 0.f, 0.f, 0.f};
#pragma unroll
                for (int kf = 0; kf < 4; kf++) {
                    int row = nt * 16 + lo;
                    int lch = 2 * kf + (hi >> 1);
                    long kf8 = *(const long*)&Ks8[cur][row * 128 +
                                ((lch ^ (row & 7)) * 16) + (hi & 1) * 8];
                    a  = __builtin_amdgcn_mfma_f32_16x16x32_fp8_fp8(kf8, qa0[kf], a, 0, 0, 0);
                    bb = __builtin_amdgcn_mfma_f32_16x16x32_fp8_fp8(kf8, qa1[kf], bb, 0, 0, 0);
                }
                sc0[nt] = a; sc1[nt] = bb;
            }
            __builtin_amdgcn_s_setprio(0);

            // causal mask (wave-uniform guard per subtile)
            if (t * 128 + 127 > qbase) {
                int qg = qbase + lo;
#pragma unroll
                for (int nt = 0; nt < 8; nt++)
#pragma unroll
                    for (int r = 0; r < 4; r++) {
                        int kg = t * 128 + nt * 16 + hi * 4 + r;
                        if (kg > qg) sc0[nt][r] = -1e30f;
                    }
            }
            if (t * 128 + 127 > qbase + 16) {
                int qg = qbase + 16 + lo;
#pragma unroll
                for (int nt = 0; nt < 8; nt++)
#pragma unroll
                    for (int r = 0; r < 4; r++) {
                        int kg = t * 128 + nt * 16 + hi * 4 + r;
                        if (kg > qg) sc1[nt][r] = -1e30f;
                    }
            }

            SM(sc0, Mr0, Lr0, o0);
            SM(sc1, Mr1, Lr1, o1);

            // PV in two 64-kv halves; Ps writes/reads are plain aliasing LDS
            // ops: compiler preserves order + inserts counted lgkm waits.
#pragma unroll
            for (int hh = 0; hh < 2; hh++) {
#pragma unroll
                for (int ntl = 0; ntl < 4; ntl++) {
                    int nt = hh * 4 + ntl;
                    bf16x4 p0, p1;
#pragma unroll
                    for (int r = 0; r < 4; r++) { p0[r] = (__bf16)sc0[nt][r]; p1[r] = (__bf16)sc1[nt][r]; }
                    int off = lo * 128 + ((ntl * 32 + hi * 8) ^ ((lo & 7) << 4));
                    *(bf16x4*)(PsW + off)        = p0;
                    *(bf16x4*)(PsW + 2048 + off) = p1;
                }
                bf16x8 pf0[2], pf1[2];
#pragma unroll
                for (int c = 0; c < 2; c++) {
                    int off = lo * 128 + ((c * 64 + hi * 16) ^ ((lo & 7) << 4));
                    pf0[c] = *(const bf16x8*)(PsW + off);
                    pf1[c] = *(const bf16x8*)(PsW + 2048 + off);
                }
                __builtin_amdgcn_s_setprio(1);
#pragma unroll
                for (int dt = 0; dt < 8; dt++) {
                    int rowd = dt * 16 + lo;
#pragma unroll
                    for (int c = 0; c < 2; c++) {
                        int gch = hh * 8 + c * 4 + hi;   // chunk in 16-wide row
                        bf16x8 vv = *(const bf16x8*)&Vs[cur][rowd * 128 +
                                     (gch ^ (rowd & 15)) * 8];
                        o0[dt] = __builtin_amdgcn_mfma_f32_16x16x32_bf16(vv, pf0[c], o0[dt], 0, 0, 0);
                        o1[dt] = __builtin_amdgcn_mfma_f32_16x16x32_bf16(vv, pf1[c], o1[dt], 0, 0, 0);
                    }
                }
                __builtin_amdgcn_s_setprio(0);
            }
            __syncthreads();  // drains prefetch; protects both bufs before reuse
            cur ^= 1;
        }

        // epilogue per subtile: O^T -> Ps -> coalesced bf16x8 stores
        const int qe = lane >> 2, c4 = lane & 3;
#pragma unroll
        for (int sub = 0; sub < 2; sub++) {
            float rl = 1.0f / (sub ? Lr1 : Lr0);
            char* Pp = PsW + sub * 2048;
#pragma unroll
            for (int h2 = 0; h2 < 2; h2++) {
#pragma unroll
                for (int dt4 = 0; dt4 < 4; dt4++) {
                    f32x4 ov = sub ? o1[h2 * 4 + dt4] : o0[h2 * 4 + dt4];
                    bf16x4 w;
#pragma unroll
                    for (int r = 0; r < 4; r++) w[r] = (__bf16)(ov[r] * rl);
                    *(bf16x4*)(Pp + lo * 128 + ((dt4 * 32 + hi * 8) ^ ((lo & 7) << 4))) = w;
                }
#pragma unroll
                for (int s2 = 0; s2 < 2; s2++) {
                    int ch = c4 + s2 * 4;
                    bf16x8 v = *(const bf16x8*)(Pp + qe * 128 + ((ch * 16) ^ ((qe & 7) << 4)));
                    int qg = qbase + sub * 16 + qe;
                    int col = h * HD + h2 * 64 + ch * 8;
                    *(bf16x8*)&ob[(size_t)(b * S_LEN + qg) * HID + col] = v;
                }
            }
        }
    }
}

// ----------------------------------- host -----------------------------------
extern "C" void kernel_launch(void* const* d_in, const int* in_sizes, int n_in,
                              void* d_out, int out_size, void* d_ws, size_t ws_size,
                              hipStream_t stream) {
    (void)in_sizes; (void)n_in; (void)out_size; (void)ws_size;
    const float* x    = (const float*)d_in[0];
    const float* cosp = (const float*)d_in[1];
    const float* sinp = (const float*)d_in[2];
    const float* Wq   = (const float*)d_in[3];
    const float* Wk   = (const float*)d_in[4];
    const float* Wv   = (const float*)d_in[5];
    const float* Wo   = (const float*)d_in[6];
    float* out = (float*)d_out;

    char* ws = (char*)d_ws;
    __bf16*        xb   = (__bf16*)(ws);               // [8192][2048] bf16  32 MB
    __bf16*        wqt  = (__bf16*)(ws + 33554432);    // [2048][2048]        8 MB
    __bf16*        wkvt = (__bf16*)(ws + 41943040);    // [1024][2048] (k|v)  4 MB (contig with wqt)
    __bf16*        wot  = (__bf16*)(ws + 46137344);    // [2048][2048]        8 MB
    unsigned char* qb8  = (unsigned char*)(ws + 54525952);  // [8192][2048] fp8 16 MB
    unsigned char* kb8  = (unsigned char*)(ws + 71303168);  // [8192][512]  fp8  4 MB
    __bf16*        vtb  = (__bf16*)(ws + 75497472);    // [16][128][2048] bf16 8 MB
    __bf16*        aob  = xb;                          // reuse xb after QKV GEMMs

    k_conv_x<<<MTOT * HID / 8 / 256, 256, 0, stream>>>(x, xb);
    { dim3 g(32, 32, 4);
      k_transpose_all<<<g, 256, 0, stream>>>(Wq, Wk, Wv, Wo, wqt, wkvt, wot); }

    k_gemm_q8<<<256, 512, 0, stream>>>(xb, wqt, qb8, cosp, sinp);
    k_gemm_kv8<<<256, 512, 0, stream>>>(xb, wqt, kb8, vtb, cosp, sinp);

    { dim3 g(NQT2 / 2, 16, BATCH); k_attn<<<g, 512, 0, stream>>>(qb8, kb8, vtb, aob); }

    k_gemm_o8<<<256, 512, 0, stream>>>(aob, wot, out);
}

// Round 19
// 306.255 us; speedup vs baseline: 1.0202x; 1.0202x over previous
//
#include <hip/hip_runtime.h>
#include <stdint.h>

#define S_LEN 2048
#define BATCH 4
#define HID   2048
#define HD    128
#define NKV   4
#define MTOT  (BATCH*S_LEN) // 8192
#define NQT2  (S_LEN/256)   // 8 q-tiles (256 rows) per (b,h)
#define QSCALE 0.08838834764831845f
#define LOG2E  1.4426950408889634f

// native v_exp_f32 (2^x)
#define EXP2F(x) __builtin_amdgcn_exp2f(x)

typedef float    f32x4  __attribute__((ext_vector_type(4)));
typedef __bf16   bf16x8 __attribute__((ext_vector_type(8)));
typedef __bf16   bf16x4 __attribute__((ext_vector_type(4)));
typedef unsigned u32x2  __attribute__((ext_vector_type(2)));

// async global->LDS, 16B per lane. LDS dest = wave-uniform base + lane*16.
__device__ __forceinline__ void gld16(const void* g, void* l) {
    __builtin_amdgcn_global_load_lds(
        (const __attribute__((address_space(1))) void*)g,
        (__attribute__((address_space(3))) void*)l, 16, 0, 0);
}

// ---------------- fp32 -> bf16 bulk convert (8 elems/thread) ----------------
__global__ void k_conv_x(const float* __restrict__ in, __bf16* __restrict__ out) {
    int i = blockIdx.x * blockDim.x + threadIdx.x;
    f32x4 a = ((const f32x4*)in)[2 * i];
    f32x4 b = ((const f32x4*)in)[2 * i + 1];
    bf16x8 o;
    o[0] = (__bf16)a[0]; o[1] = (__bf16)a[1]; o[2] = (__bf16)a[2]; o[3] = (__bf16)a[3];
    o[4] = (__bf16)b[0]; o[5] = (__bf16)b[1]; o[6] = (__bf16)b[2]; o[7] = (__bf16)b[3];
    ((bf16x8*)out)[i] = o;
}

// ---- ALL weight transposes in one launch: W [K][N] fp32 -> Wt [N][K] bf16 --
__global__ void k_transpose_all(const float* __restrict__ Wq,
                                const float* __restrict__ Wk,
                                const float* __restrict__ Wv,
                                const float* __restrict__ Wo,
                                __bf16* __restrict__ wqt,
                                __bf16* __restrict__ wkvt,
                                __bf16* __restrict__ wot) {
    const int z = blockIdx.z;
    const float* in; __bf16* out; int N;
    if      (z == 0) { in = Wq; out = wqt;  N = 2048; }
    else if (z == 1) { in = Wk; out = wkvt; N = 512;  }
    else if (z == 2) { in = Wv; out = wkvt + (size_t)512 * HID; N = 512; }
    else             { in = Wo; out = wot;  N = 2048; }
    int k0 = blockIdx.x * 64, n0 = blockIdx.y * 64;
    if (n0 >= N) return;
    __shared__ float tile[64][65];
    for (int e = threadIdx.x; e < 4096; e += 256) {
        int r = e >> 6, c = e & 63;
        tile[r][c] = in[(size_t)(k0 + r) * N + n0 + c];
    }
    __syncthreads();
    for (int e = threadIdx.x; e < 4096; e += 256) {
        int r = e >> 6, c = e & 63;
        out[(size_t)(n0 + r) * HID + k0 + c] = (__bf16)tile[c][r];
    }
}

// ============== 8-phase deep-pipeline K-loop (validated R13) ================
// Barriers MUST be memory-fenced asm ("s_barrier" ::: "memory"): the bare
// builtin is IntrNoMem and the compiler hoists ds_reads across it (R12 race).
#define BARM asm volatile("s_barrier" ::: "memory")
#define BAR1 do { BARM;                                                       \
                  asm volatile("s_waitcnt lgkmcnt(0)" ::: "memory");          \
                  __builtin_amdgcn_sched_barrier(0); } while (0)
#define BAR2 BARM
#define MM(qm, qn)                                                            \
    do {                                                                      \
        __builtin_amdgcn_s_setprio(1);                                        \
        _Pragma("unroll") for (int ks = 0; ks < 2; ks++)                      \
        _Pragma("unroll") for (int mf = 0; mf < 4; mf++)                      \
        _Pragma("unroll") for (int nf = 0; nf < 2; nf++)                      \
            acc[qm][qn][mf][nf] = __builtin_amdgcn_mfma_f32_16x16x32_bf16(    \
                af[mf][ks], bf[nf][ks], acc[qm][qn][mf][nf], 0, 0, 0);        \
        __builtin_amdgcn_s_setprio(0);                                        \
    } while (0)

// The shared 8-phase K-loop body (BM=BN=256, BK=64, 8 waves 2Mx4N, K=2048,
// LDS 128 KiB). Declares Ab/Bb/acc/af/bf and runs the full 16-iteration loop.
#define GEMM8_BODY(Aptr, Bptr)                                                \
    __shared__ __bf16 Ab[2][2][128 * 64];                                     \
    __shared__ __bf16 Bb[2][2][128 * 64];                                     \
    const int tid = threadIdx.x, lane = tid & 63, wave = tid >> 6;            \
    const int wm = wave >> 2, wn = wave & 3;                                  \
    const int lo = lane & 15, hi = lane >> 4;                                 \
    f32x4 acc[2][2][4][2] = {};                                               \
    const int srow = wave * 8 + (lane >> 3);                                  \
    const int sp   = lane & 7;                                                \
    auto STA = [&](int s, int h, int t) {                                     \
        _Pragma("unroll") for (int p = 0; p < 2; p++) {                       \
            int rr = p * 64 + srow;                                           \
            int c = sp ^ (rr & 7);                                            \
            gld16(Aptr + (size_t)(m0 + h * 128 + rr) * HID + t * 64 + c * 8,  \
                  &Ab[s][h][(p * 64 + wave * 8) * 64]);                       \
        }                                                                     \
    };                                                                        \
    auto STB = [&](int s, int h, int t) {                                     \
        _Pragma("unroll") for (int p = 0; p < 2; p++) {                       \
            int rr = p * 64 + srow;                                           \
            int c = sp ^ (rr & 7);                                            \
            gld16(Bptr + (size_t)(n0 + h * 128 + rr) * HID + t * 64 + c * 8,  \
                  &Bb[s][h][(p * 64 + wave * 8) * 64]);                       \
        }                                                                     \
    };                                                                        \
    bf16x8 af[4][2], bf[2][2];                                                \
    auto LDA = [&](int s, int qm) {                                           \
        _Pragma("unroll") for (int mf = 0; mf < 4; mf++) {                    \
            int rr = wm * 64 + mf * 16 + lo;                                  \
            _Pragma("unroll") for (int ks = 0; ks < 2; ks++) {                \
                int pp = (ks * 4 + hi) ^ (rr & 7);                            \
                af[mf][ks] = *(const bf16x8*)&Ab[s][qm][rr * 64 + pp * 8];    \
            }                                                                 \
        }                                                                     \
    };                                                                        \
    auto LDB = [&](int s, int qn) {                                           \
        _Pragma("unroll") for (int nf = 0; nf < 2; nf++) {                    \
            int rr = wn * 32 + nf * 16 + lo;                                  \
            _Pragma("unroll") for (int ks = 0; ks < 2; ks++) {                \
                int pp = (ks * 4 + hi) ^ (rr & 7);                            \
                bf[nf][ks] = *(const bf16x8*)&Bb[s][qn][rr * 64 + pp * 8];    \
            }                                                                 \
        }                                                                     \
    };                                                                        \
    STA(0, 0, 0); STB(0, 0, 0); STA(0, 1, 0); STB(0, 1, 0);                   \
    STA(1, 1, 1); STB(1, 1, 1);                                               \
    asm volatile("s_waitcnt vmcnt(4)" ::: "memory");                          \
    BARM;                                                                     \
    _Pragma("unroll 1")                                                       \
    for (int i = 0; i < 16; i++) {                                            \
        const int t0 = 2 * i, t1 = 2 * i + 1;                                 \
        const bool more = (i < 15);                                           \
        LDA(0, 0); LDB(0, 0);                                                 \
        STA(1, 0, t1); STB(1, 0, t1);                                         \
        BAR1; MM(0, 0); BAR2;                                                 \
        LDB(0, 1);                                                            \
        BAR1; MM(0, 1); BAR2;                                                 \
        LDA(0, 1); LDB(0, 0);                                                 \
        if (more) STA(0, 0, t0 + 2);                                          \
        BAR1; MM(1, 0); BAR2;                                                 \
        LDB(0, 1);                                                            \
        if (more) STB(0, 0, t0 + 2);                                          \
        BAR1; MM(1, 1);                                                       \
        if (more) { asm volatile("s_waitcnt vmcnt(4)" ::: "memory"); }        \
        else      { asm volatile("s_waitcnt vmcnt(0)" ::: "memory"); }        \
        BAR2;                                                                 \
        LDA(1, 1); LDB(1, 1);                                                 \
        if (more) { STA(0, 1, t0 + 2); STB(0, 1, t0 + 2); }                   \
        BAR1; MM(1, 1); BAR2;                                                 \
        LDB(1, 0);                                                            \
        BAR1; MM(1, 0); BAR2;                                                 \
        LDA(1, 0); LDB(1, 1);                                                 \
        if (more) STA(1, 1, t1 + 2);                                          \
        BAR1; MM(0, 1); BAR2;                                                 \
        LDB(1, 0);                                                            \
        if (more) STB(1, 1, t1 + 2);                                          \
        BAR1; MM(0, 0);                                                       \
        if (more) { asm volatile("s_waitcnt vmcnt(4)" ::: "memory"); }        \
        BAR2;                                                                 \
    }

// -------- Q-proj GEMM, 8-phase: qb8 fp8 = rope(xb*wqt^T)*QSCALE*log2e -------
// grid 256 = (m 32) x (n 8) = exactly 1 block/CU. log2e folded into the fp8
// scale so k_attn's softmax can use native exp2 (v_exp_f32).
__global__ __launch_bounds__(512) void k_gemm_q8(const __bf16* __restrict__ A,
                                                 const __bf16* __restrict__ Bt,
                                                 unsigned char* __restrict__ qb8,
                                                 const float* __restrict__ cosp,
                                                 const float* __restrict__ sinp) {
    const int m0 = (blockIdx.x >> 3) * 256;
    const int n0 = (blockIdx.x & 7) * 256;
    GEMM8_BODY(A, Bt)

    // epilogue: per-quadrant LDS stage -> rope + scale + fp8 -> store.
    __bf16* Cs = (__bf16*)&Ab[0][0][0];            // [128][132]
    const int crow = tid >> 4;                     // 0..31 (+32 per rep)
    const int cch  = tid & 15;                     // 8-col chunk
    const int d0 = cch * 8;
    const float QS2 = QSCALE * LOG2E;
#pragma unroll
    for (int qm = 0; qm < 2; qm++)
#pragma unroll
        for (int qn = 0; qn < 2; qn++) {
#pragma unroll
            for (int mf = 0; mf < 4; mf++)
#pragma unroll
                for (int nf = 0; nf < 2; nf++) {
                    int rl = wm * 64 + mf * 16 + hi * 4;
                    int cl = wn * 32 + nf * 16 + lo;
#pragma unroll
                    for (int r = 0; r < 4; r++)
                        Cs[(rl + r) * 132 + cl] = (__bf16)acc[qm][qn][mf][nf][r];
                }
            __syncthreads();
#pragma unroll
            for (int rep = 0; rep < 4; rep++) {
                int row = rep * 32 + crow;
                int rowg = m0 + qm * 128 + row;
                int colg = n0 + qn * 128 + cch * 8;
                bf16x8 v = *(const bf16x8*)&Cs[row * 132 + cch * 8];
                float f[8];
#pragma unroll
                for (int j = 0; j < 8; j++) f[j] = (float)v[j];
                int s = rowg & (S_LEN - 1);
                f32x4 c0 = *(const f32x4*)&cosp[s * HD + d0];
                f32x4 c1 = *(const f32x4*)&cosp[s * HD + d0 + 4];
                f32x4 s0 = *(const f32x4*)&sinp[s * HD + d0];
                f32x4 s1 = *(const f32x4*)&sinp[s * HD + d0 + 4];
                float cc[8] = {c0[0], c0[1], c0[2], c0[3], c1[0], c1[1], c1[2], c1[3]};
                float ss[8] = {s0[0], s0[1], s0[2], s0[3], s1[0], s1[1], s1[2], s1[3]};
#pragma unroll
                for (int p = 0; p < 4; p++) {
                    float e0 = f[2 * p], e1 = f[2 * p + 1];
                    f[2 * p]     = (e0 * cc[2 * p]     - e1 * ss[2 * p])     * QS2;
                    f[2 * p + 1] = (e1 * cc[2 * p + 1] + e0 * ss[2 * p + 1]) * QS2;
                }
                int u0 = __builtin_amdgcn_cvt_pk_fp8_f32(f[0], f[1], 0, false);
                u0     = __builtin_amdgcn_cvt_pk_fp8_f32(f[2], f[3], u0, true);
                int u1 = __builtin_amdgcn_cvt_pk_fp8_f32(f[4], f[5], 0, false);
                u1     = __builtin_amdgcn_cvt_pk_fp8_f32(f[6], f[7], u1, true);
                u32x2 pk; pk[0] = (unsigned)u0; pk[1] = (unsigned)u1;
                *(u32x2*)&qb8[(size_t)rowg * HID + colg] = pk;
            }
            __syncthreads();
        }
}

// -------- O-proj GEMM, 8-phase (validated R13): out[8192][2048] f32 ---------
__global__ __launch_bounds__(512) void k_gemm_o8(const __bf16* __restrict__ A,
                                                 const __bf16* __restrict__ Bt,
                                                 float* __restrict__ Cp) {
    const int m0 = (blockIdx.x >> 3) * 256;
    const int n0 = (blockIdx.x & 7) * 256;
    GEMM8_BODY(A, Bt)

#pragma unroll
    for (int qm = 0; qm < 2; qm++)
#pragma unroll
        for (int qn = 0; qn < 2; qn++)
#pragma unroll
            for (int mf = 0; mf < 4; mf++)
#pragma unroll
                for (int nf = 0; nf < 2; nf++) {
                    int row = m0 + qm * 128 + wm * 64 + mf * 16 + hi * 4;
                    int col = n0 + qn * 128 + wn * 32 + nf * 16 + lo;
#pragma unroll
                    for (int r = 0; r < 4; r++)
                        Cp[(size_t)(row + r) * HID + col] = acc[qm][qn][mf][nf][r];
                }
}

// ---- KV-proj GEMM (m97 structure, R17-validated): C[8192][1024] ------------
// grid (64, 8): n0 = 2048 + by*128. cols [2048,2560) -> k rope+fp8 -> kb8;
// [2560,3072) -> v transposed -> vtb. NOTE: K gets NO log2e (Q carries it).
// R18's 4-phase port regressed (+13 us total) -> reverted per pre-commitment.
__global__ __launch_bounds__(256) void k_gemm_kv(const __bf16* __restrict__ A,
                                                 const __bf16* __restrict__ Bt,
                                                 unsigned char* __restrict__ kb8,
                                                 __bf16* __restrict__ vtb,
                                                 const float* __restrict__ cosp,
                                                 const float* __restrict__ sinp) {
    __shared__ __align__(16) char smem[33792];
    __bf16* As = (__bf16*)smem;
    __bf16* Bs = (__bf16*)(smem + 16384);
    const int tid = threadIdx.x, lane = tid & 63, wave = tid >> 6;
    const int wm = wave >> 1, wn = wave & 1;
    const int m0 = blockIdx.x * 128;
    const int n0 = 2048 + blockIdx.y * 128;
    const int lo = lane & 15, hi = lane >> 4;
    f32x4 acc[4][4] = {};

    const int srow = wave * 8 + (lane >> 3);
    const int sp   = lane & 7;

    for (int kt = 0; kt < HID; kt += 64) {
#pragma unroll
        for (int r = 0; r < 4; r++) {
            int row = r * 32 + srow;
            int c = sp ^ (row & 7);
            gld16(A + (size_t)(m0 + row) * HID + kt + c * 8, &As[(r * 32 + wave * 8) * 64]);
        }
#pragma unroll
        for (int r = 0; r < 4; r++) {
            int row = r * 32 + srow;
            int c = sp ^ (row & 7);
            gld16(Bt + (size_t)(n0 + row) * HID + kt + c * 8, &Bs[(r * 32 + wave * 8) * 64]);
        }
        __syncthreads();
#pragma unroll
        for (int ks = 0; ks < 2; ks++) {
            bf16x8 af[4], bfr[4];
#pragma unroll
            for (int mt = 0; mt < 4; mt++) {
                int row = wm * 64 + mt * 16 + lo;
                int pp = (ks * 4 + hi) ^ (row & 7);
                af[mt] = *(const bf16x8*)&As[row * 64 + pp * 8];
            }
#pragma unroll
            for (int nt = 0; nt < 4; nt++) {
                int row = wn * 64 + nt * 16 + lo;
                int pp = (ks * 4 + hi) ^ (row & 7);
                bfr[nt] = *(const bf16x8*)&Bs[row * 64 + pp * 8];
            }
#pragma unroll
            for (int mt = 0; mt < 4; mt++)
#pragma unroll
                for (int nt = 0; nt < 4; nt++)
                    acc[mt][nt] = __builtin_amdgcn_mfma_f32_16x16x32_bf16(
                        af[mt], bfr[nt], acc[mt][nt], 0, 0, 0);
        }
        __syncthreads();
    }

    if (n0 < 2560) {
        __bf16* Cs = (__bf16*)smem;                 // [128][132]
#pragma unroll
        for (int mt = 0; mt < 4; mt++)
#pragma unroll
            for (int nt = 0; nt < 4; nt++) {
                int rl = wm * 64 + mt * 16 + hi * 4;
                int cl = wn * 64 + nt * 16 + lo;
#pragma unroll
                for (int r = 0; r < 4; r++)
                    Cs[(rl + r) * 132 + cl] = (__bf16)acc[mt][nt][r];
            }
        __syncthreads();

        const int crow = tid >> 4;
        const int cch  = tid & 15;
        const int colg = n0 + cch * 8;
        const int d0 = colg & (HD - 1);
#pragma unroll
        for (int rep = 0; rep < 8; rep++) {
            int row = rep * 16 + crow;
            int rowg = m0 + row;
            bf16x8 v = *(const bf16x8*)&Cs[row * 132 + cch * 8];
            float f[8];
#pragma unroll
            for (int j = 0; j < 8; j++) f[j] = (float)v[j];
            int s = rowg & (S_LEN - 1);
            f32x4 c0 = *(const f32x4*)&cosp[s * HD + d0];
            f32x4 c1 = *(const f32x4*)&cosp[s * HD + d0 + 4];
            f32x4 s0 = *(const f32x4*)&sinp[s * HD + d0];
            f32x4 s1 = *(const f32x4*)&sinp[s * HD + d0 + 4];
            float cc[8] = {c0[0], c0[1], c0[2], c0[3], c1[0], c1[1], c1[2], c1[3]};
            float ss[8] = {s0[0], s0[1], s0[2], s0[3], s1[0], s1[1], s1[2], s1[3]};
#pragma unroll
            for (int p = 0; p < 4; p++) {
                float e0 = f[2 * p], e1 = f[2 * p + 1];
                f[2 * p]     = e0 * cc[2 * p]     - e1 * ss[2 * p];
                f[2 * p + 1] = e1 * cc[2 * p + 1] + e0 * ss[2 * p + 1];
            }
            int u0 = __builtin_amdgcn_cvt_pk_fp8_f32(f[0], f[1], 0, false);
            u0     = __builtin_amdgcn_cvt_pk_fp8_f32(f[2], f[3], u0, true);
            int u1 = __builtin_amdgcn_cvt_pk_fp8_f32(f[4], f[5], 0, false);
            u1     = __builtin_amdgcn_cvt_pk_fp8_f32(f[6], f[7], u1, true);
            u32x2 pk; pk[0] = (unsigned)u0; pk[1] = (unsigned)u1;
            *(u32x2*)&kb8[(size_t)rowg * 512 + (colg - 2048)] = pk;
        }
    } else {
        __bf16* CsT = (__bf16*)smem;                // [128 cols][132 rows pad]
#pragma unroll
        for (int mt = 0; mt < 4; mt++)
#pragma unroll
            for (int nt = 0; nt < 4; nt++) {
                int cl = wn * 64 + nt * 16 + lo;
                int mrow = wm * 64 + mt * 16 + hi * 4;
                bf16x4 w;
#pragma unroll
                for (int r = 0; r < 4; r++) w[r] = (__bf16)acc[mt][nt][r];
                *(bf16x4*)&CsT[cl * 132 + mrow] = w;
            }
        __syncthreads();

        const int kvh = (n0 - 2560) >> 7;
        const int bb = m0 >> 11;
        const int s0 = m0 & (S_LEN - 1);
        __bf16* dst = vtb + (size_t)(bb * NKV + kvh) * HD * S_LEN;
        const int dloc = tid >> 4;
        const int sch  = tid & 15;
#pragma unroll
        for (int rep = 0; rep < 8; rep++) {
            int d = rep * 16 + dloc;
            bf16x8 v = *(const bf16x8*)&CsT[d * 132 + sch * 8];
            *(bf16x8*)&dst[(size_t)d * S_LEN + s0 + sch * 8] = v;
        }
    }
}

// ----------------------------- flash attention ------------------------------
// KVBLK=128; QK^T fp8 (Q pre-scaled by QSCALE*log2e -> native exp2 softmax).
// PV bf16 in two 64-kv halves via wave-private Ps. LDS-throughput-bound
// (~816 cyc/wave/tile model matches 100us measured).
// LDS: Ks8 2x16K + Vs 2x32K + Ps 32K = 128 KB. Grid 256 = 1/CU.
__global__ __launch_bounds__(512) void k_attn(const unsigned char* __restrict__ qb8,
                                              const unsigned char* __restrict__ kb8,
                                              const __bf16* __restrict__ vtb,
                                              __bf16* __restrict__ ob) {
    __shared__ char   Ks8[2][128 * 128];  // [kv][128B fp8 d], 8-chunk XOR swz
    __shared__ __bf16 Vs[2][128 * 128];   // [d][kv 128] bf16, 16-chunk XOR swz
    __shared__ __bf16 Ps[8][2048];        // wave-private: 2 subtiles x 16x64
    const int tid = threadIdx.x, lane = tid & 63, wave = tid >> 6;
    const int pair = blockIdx.x, h = blockIdx.y, b = blockIdx.z;
    const int kvh = h >> 2;
    const int lo = lane & 15, hi = lane >> 4;
    char* PsW = (char*)&Ps[wave][0];

    const unsigned char* kbb = kb8 + (size_t)b * S_LEN * 512 + kvh * HD;
    const __bf16* vbb = vtb + (size_t)(b * NKV + kvh) * HD * S_LEN;

    const int krow_s = tid >> 3;                // 0..63 (+64 per round)
    const int kp_s   = tid & 7;
    const int vrow_s = tid >> 4;                // 0..31 (+32 per round)
    const int vp_s   = tid & 15;

    auto STAGE_K = [&](int buf, int t) {        // 16 KB: 2 gld16 rounds
#pragma unroll
        for (int r = 0; r < 2; r++) {
            int row = r * 64 + krow_s;
            int c = kp_s ^ (row & 7);
            gld16(kbb + (size_t)(t * 128 + row) * 512 + c * 16,
                  &Ks8[buf][(r * 64 + wave * 8) * 128]);
        }
    };
    auto STAGE_V = [&](int buf, int t) {        // 32 KB: 4 gld16 rounds
#pragma unroll
        for (int r = 0; r < 4; r++) {
            int row = r * 32 + vrow_s;          // d-row
            int c = vp_s ^ (row & 15);
            gld16(vbb + (size_t)row * S_LEN + t * 128 + c * 8,
                  &Vs[buf][(r * 32 + wave * 4) * 128]);
        }
    };

    // online softmax over 32 in-lane scores (exp2 domain; T13 defer thr=8)
    auto SM = [&](f32x4 (&sc)[8], float& Mr, float& Lr, f32x4 (&o)[8]) {
        float mloc = sc[0][0];
#pragma unroll
        for (int nt = 0; nt < 8; nt++)
#pragma unroll
            for (int r = 0; r < 4; r++) mloc = fmaxf(mloc, sc[nt][r]);
        mloc = fmaxf(mloc, __shfl_xor(mloc, 16, 64));
        mloc = fmaxf(mloc, __shfl_xor(mloc, 32, 64));
        float mn = (mloc <= Mr + 8.f) ? Mr : mloc;
        float sum = 0.f;
#pragma unroll
        for (int nt = 0; nt < 8; nt++)
#pragma unroll
            for (int r = 0; r < 4; r++) {
                float e = EXP2F(sc[nt][r] - mn);
                sc[nt][r] = e;
                sum += e;
            }
        sum += __shfl_xor(sum, 16, 64);
        sum += __shfl_xor(sum, 32, 64);
        if (mn != Mr) {
            float scl = EXP2F(Mr - mn);
            Lr = Lr * scl + sum;
            Mr = mn;
#pragma unroll
            for (int dt = 0; dt < 8; dt++) o[dt] *= scl;
        } else {
            Lr += sum;
        }
    };

#pragma unroll 1
    for (int pi = 0; pi < 2; pi++) {
        const int qt = pi ? (NQT2 - 1 - pair) : pair;  // 256-row q-tile index
        const int nkv = 2 * qt + 2;                    // kv tiles of 128 rows
        const int qbase = qt * 256 + wave * 32;        // this wave's 32 q-rows

        const unsigned char* qp0 = qb8 + (size_t)(b * S_LEN + qbase + lo) * HID + h * HD;
        const unsigned char* qp1 = qp0 + (size_t)16 * HID;
        long qa0[4], qa1[4];
#pragma unroll
        for (int kf = 0; kf < 4; kf++) {
            qa0[kf] = *(const long*)(qp0 + kf * 32 + hi * 8);
            qa1[kf] = *(const long*)(qp1 + kf * 32 + hi * 8);
        }

        f32x4 o0[8] = {}, o1[8] = {};
        float Mr0 = -3e30f, Lr0 = 0.f, Mr1 = -3e30f, Lr1 = 0.f;

        int cur = 0;
        if (pi == 1) __syncthreads();
        STAGE_K(0, 0);
        STAGE_V(0, 0);
        __syncthreads();

#pragma unroll 1
        for (int t = 0; t < nkv; t++) {
            if (t < nkv - 1) { STAGE_K(cur ^ 1, t + 1); STAGE_V(cur ^ 1, t + 1); }

            // S^T = K Q^T (fp8), 8 nt-rows of 16 kv, both subtiles share K
            f32x4 sc0[8], sc1[8];
            __builtin_amdgcn_s_setprio(1);
#pragma unroll
            for (int nt = 0; nt < 8; nt++) {
                f32x4 a = {0.f, 0.f, 0.f, 0.f}, bb = {0.f, 0.f, 0.f, 0.f};
#pragma unroll
                for (int kf = 0; kf < 4; kf++) {
                    int row = nt * 16 + lo;
                    int lch = 2 * kf + (hi >> 1);
                    long kf8 = *(const long*)&Ks8[cur][row * 128 +
                                ((lch ^ (row & 7)) * 16) + (hi & 1) * 8];
                    a  = __builtin_amdgcn_mfma_f32_16x16x32_fp8_fp8(kf8, qa0[kf], a, 0, 0, 0);
                    bb = __builtin_amdgcn_mfma_f32_16x16x32_fp8_fp8(kf8, qa1[kf], bb, 0, 0, 0);
                }
                sc0[nt] = a; sc1[nt] = bb;
            }
            __builtin_amdgcn_s_setprio(0);

            // causal mask (wave-uniform guard per subtile)
            if (t * 128 + 127 > qbase) {
                int qg = qbase + lo;
#pragma unroll
                for (int nt = 0; nt < 8; nt++)
#pragma unroll
                    for (int r = 0; r < 4; r++) {
                        int kg = t * 128 + nt * 16 + hi * 4 + r;
                        if (kg > qg) sc0[nt][r] = -1e30f;
                    }
            }
            if (t * 128 + 127 > qbase + 16) {
                int qg = qbase + 16 + lo;
#pragma unroll
                for (int nt = 0; nt < 8; nt++)
#pragma unroll
                    for (int r = 0; r < 4; r++) {
                        int kg = t * 128 + nt * 16 + hi * 4 + r;
                        if (kg > qg) sc1[nt][r] = -1e30f;
                    }
            }

            SM(sc0, Mr0, Lr0, o0);
            SM(sc1, Mr1, Lr1, o1);

            // PV in two 64-kv halves; Ps writes/reads are plain aliasing LDS
            // ops: compiler preserves order + inserts counted lgkm waits.
#pragma unroll
            for (int hh = 0; hh < 2; hh++) {
#pragma unroll
                for (int ntl = 0; ntl < 4; ntl++) {
                    int nt = hh * 4 + ntl;
                    bf16x4 p0, p1;
#pragma unroll
                    for (int r = 0; r < 4; r++) { p0[r] = (__bf16)sc0[nt][r]; p1[r] = (__bf16)sc1[nt][r]; }
                    int off = lo * 128 + ((ntl * 32 + hi * 8) ^ ((lo & 7) << 4));
                    *(bf16x4*)(PsW + off)        = p0;
                    *(bf16x4*)(PsW + 2048 + off) = p1;
                }
                bf16x8 pf0[2], pf1[2];
#pragma unroll
                for (int c = 0; c < 2; c++) {
                    int off = lo * 128 + ((c * 64 + hi * 16) ^ ((lo & 7) << 4));
                    pf0[c] = *(const bf16x8*)(PsW + off);
                    pf1[c] = *(const bf16x8*)(PsW + 2048 + off);
                }
                __builtin_amdgcn_s_setprio(1);
#pragma unroll
                for (int dt = 0; dt < 8; dt++) {
                    int rowd = dt * 16 + lo;
#pragma unroll
                    for (int c = 0; c < 2; c++) {
                        int gch = hh * 8 + c * 4 + hi;   // chunk in 16-wide row
                        bf16x8 vv = *(const bf16x8*)&Vs[cur][rowd * 128 +
                                     (gch ^ (rowd & 15)) * 8];
                        o0[dt] = __builtin_amdgcn_mfma_f32_16x16x32_bf16(vv, pf0[c], o0[dt], 0, 0, 0);
                        o1[dt] = __builtin_amdgcn_mfma_f32_16x16x32_bf16(vv, pf1[c], o1[dt], 0, 0, 0);
                    }
                }
                __builtin_amdgcn_s_setprio(0);
            }
            __syncthreads();  // drains prefetch; protects both bufs before reuse
            cur ^= 1;
        }

        // epilogue per subtile: O^T -> Ps -> coalesced bf16x8 stores
        const int qe = lane >> 2, c4 = lane & 3;
#pragma unroll
        for (int sub = 0; sub < 2; sub++) {
            float rl = 1.0f / (sub ? Lr1 : Lr0);
            char* Pp = PsW + sub * 2048;
#pragma unroll
            for (int h2 = 0; h2 < 2; h2++) {
#pragma unroll
                for (int dt4 = 0; dt4 < 4; dt4++) {
                    f32x4 ov = sub ? o1[h2 * 4 + dt4] : o0[h2 * 4 + dt4];
                    bf16x4 w;
#pragma unroll
                    for (int r = 0; r < 4; r++) w[r] = (__bf16)(ov[r] * rl);
                    *(bf16x4*)(Pp + lo * 128 + ((dt4 * 32 + hi * 8) ^ ((lo & 7) << 4))) = w;
                }
#pragma unroll
                for (int s2 = 0; s2 < 2; s2++) {
                    int ch = c4 + s2 * 4;
                    bf16x8 v = *(const bf16x8*)(Pp + qe * 128 + ((ch * 16) ^ ((qe & 7) << 4)));
                    int qg = qbase + sub * 16 + qe;
                    int col = h * HD + h2 * 64 + ch * 8;
                    *(bf16x8*)&ob[(size_t)(b * S_LEN + qg) * HID + col] = v;
                }
            }
        }
    }
}

// ----------------------------------- host -----------------------------------
extern "C" void kernel_launch(void* const* d_in, const int* in_sizes, int n_in,
                              void* d_out, int out_size, void* d_ws, size_t ws_size,
                              hipStream_t stream) {
    (void)in_sizes; (void)n_in; (void)out_size; (void)ws_size;
    const float* x    = (const float*)d_in[0];
    const float* cosp = (const float*)d_in[1];
    const float* sinp = (const float*)d_in[2];
    const float* Wq   = (const float*)d_in[3];
    const float* Wk   = (const float*)d_in[4];
    const float* Wv   = (const float*)d_in[5];
    const float* Wo   = (const float*)d_in[6];
    float* out = (float*)d_out;

    char* ws = (char*)d_ws;
    __bf16*        xb   = (__bf16*)(ws);               // [8192][2048] bf16  32 MB
    __bf16*        wqt  = (__bf16*)(ws + 33554432);    // [2048][2048]        8 MB
    __bf16*        wkvt = (__bf16*)(ws + 41943040);    // [1024][2048] (k|v)  4 MB (contig with wqt)
    __bf16*        wot  = (__bf16*)(ws + 46137344);    // [2048][2048]        8 MB
    unsigned char* qb8  = (unsigned char*)(ws + 54525952);  // [8192][2048] fp8 16 MB
    unsigned char* kb8  = (unsigned char*)(ws + 71303168);  // [8192][512]  fp8  4 MB
    __bf16*        vtb  = (__bf16*)(ws + 75497472);    // [16][128][2048] bf16 8 MB
    __bf16*        aob  = xb;                          // reuse xb after QKV GEMMs

    k_conv_x<<<MTOT * HID / 8 / 256, 256, 0, stream>>>(x, xb);
    { dim3 g(32, 32, 4);
      k_transpose_all<<<g, 256, 0, stream>>>(Wq, Wk, Wv, Wo, wqt, wkvt, wot); }

    k_gemm_q8<<<256, 512, 0, stream>>>(xb, wqt, qb8, cosp, sinp);
    { dim3 g(64, 8); k_gemm_kv<<<g, 256, 0, stream>>>(xb, wqt, kb8, vtb, cosp, sinp); }

    { dim3 g(NQT2 / 2, 16, BATCH); k_attn<<<g, 512, 0, stream>>>(qb8, kb8, vtb, aob); }

    k_gemm_o8<<<256, 512, 0, stream>>>(aob, wot, out);
}